// Round 2
// baseline (195.246 us; speedup 1.0000x reference)
//
#include <hip/hip_runtime.h>

// Problem constants (from reference): B,N,H,W = 64,21,128,128
#define BB 64
#define NN 21
#define HH 128
#define WW 128
static constexpr long long TOT_ELEMS = (long long)BB * NN * HH * WW; // 22,020,096
static constexpr int NV4 = (int)(TOT_ELEMS / 4);                     // 5,505,024 float4s
static constexpr int NKP = BB * NN;                                  // 1344 keypoints

static constexpr int BLOCKS  = 2048; // 8 blocks/CU x 256 CUs -> 100% wave occupancy at 12 VGPR
static constexpr int THREADS = 256;

// Kernel 1: grid-stride float4 MSE accumulation, 4-way unrolled for MLP.
// First NKP global threads also do the keypoint gather for soft-PCK.
// Each block writes its partial sums to its own ws slot (no init required).
__global__ __launch_bounds__(THREADS) void combined_loss_partial(
    const float4* __restrict__ pred4,
    const float4* __restrict__ gt4,
    const float*  __restrict__ pred,   // scalar view for the gather
    const float*  __restrict__ kp,     // (B,N,2) -> [x, y]
    float2* __restrict__ partial)      // partial[b] = {sum sq diff, sum (1-v)^2}
{
    const int tid    = blockIdx.x * blockDim.x + threadIdx.x;
    const int stride = gridDim.x * blockDim.x;

    float s0 = 0.0f, s1 = 0.0f, s2a = 0.0f, s3 = 0.0f;
    int i = tid;
    // 4-way unroll: 8 independent 16B loads in flight before first consumer.
    for (; i + 3 * stride < NV4; i += 4 * stride) {
        float4 p0 = pred4[i];
        float4 p1 = pred4[i + stride];
        float4 p2 = pred4[i + 2 * stride];
        float4 p3 = pred4[i + 3 * stride];
        float4 g0 = gt4[i];
        float4 g1 = gt4[i + stride];
        float4 g2 = gt4[i + 2 * stride];
        float4 g3 = gt4[i + 3 * stride];
        float d;
        d = p0.x - g0.x; s0 += d * d;  d = p0.y - g0.y; s0 += d * d;
        d = p0.z - g0.z; s0 += d * d;  d = p0.w - g0.w; s0 += d * d;
        d = p1.x - g1.x; s1 += d * d;  d = p1.y - g1.y; s1 += d * d;
        d = p1.z - g1.z; s1 += d * d;  d = p1.w - g1.w; s1 += d * d;
        d = p2.x - g2.x; s2a += d * d; d = p2.y - g2.y; s2a += d * d;
        d = p2.z - g2.z; s2a += d * d; d = p2.w - g2.w; s2a += d * d;
        d = p3.x - g3.x; s3 += d * d;  d = p3.y - g3.y; s3 += d * d;
        d = p3.z - g3.z; s3 += d * d;  d = p3.w - g3.w; s3 += d * d;
    }
    for (; i < NV4; i += stride) {
        float4 p = pred4[i];
        float4 g = gt4[i];
        float d;
        d = p.x - g.x; s0 += d * d;  d = p.y - g.y; s0 += d * d;
        d = p.z - g.z; s0 += d * d;  d = p.w - g.w; s0 += d * d;
    }
    float s = (s0 + s1) + (s2a + s3);

    // Soft-PCK gather: tid == b*N + n, heatmap base offset = tid*H*W.
    float s2 = 0.0f;
    if (tid < NKP) {
        float px = kp[2 * tid + 0];
        float py = kp[2 * tid + 1];
        // jnp.clip(v, 0, dim-1).astype(int32): clamp then truncate toward zero
        int xi = (int)fminf(fmaxf(px, 0.0f), (float)(WW - 1));
        int yi = (int)fminf(fmaxf(py, 0.0f), (float)(HH - 1));
        float v = pred[(long long)tid * HH * WW + (long long)yi * WW + xi];
        float dd = 1.0f - v;
        s2 = dd * dd;
    }

    // Wave-64 reduce
    #pragma unroll
    for (int off = 32; off > 0; off >>= 1) {
        s  += __shfl_down(s,  off, 64);
        s2 += __shfl_down(s2, off, 64);
    }

    __shared__ float ls[4], ls2[4]; // 256 threads / 64 = 4 waves
    const int lane = threadIdx.x & 63;
    const int wid  = threadIdx.x >> 6;
    if (lane == 0) { ls[wid] = s; ls2[wid] = s2; }
    __syncthreads();
    if (threadIdx.x == 0) {
        float t  = (ls[0] + ls[1]) + (ls[2] + ls[3]);
        float t2 = (ls2[0] + ls2[1]) + (ls2[2] + ls2[3]);
        partial[blockIdx.x] = make_float2(t, t2);
    }
}

// Kernel 2: one block reduces the 2048 per-block partials and writes out.
__global__ __launch_bounds__(THREADS) void combined_loss_final(
    const float2* __restrict__ partial,
    float* __restrict__ out)
{
    float s = 0.0f, s2 = 0.0f;
    for (int i = threadIdx.x; i < BLOCKS; i += THREADS) {
        float2 p = partial[i];
        s += p.x; s2 += p.y;
    }
    #pragma unroll
    for (int off = 32; off > 0; off >>= 1) {
        s  += __shfl_down(s,  off, 64);
        s2 += __shfl_down(s2, off, 64);
    }
    __shared__ float ls[4], ls2[4];
    const int lane = threadIdx.x & 63;
    const int wid  = threadIdx.x >> 6;
    if (lane == 0) { ls[wid] = s; ls2[wid] = s2; }
    __syncthreads();
    if (threadIdx.x == 0) {
        float t  = (ls[0] + ls[1]) + (ls[2] + ls[3]);
        float t2 = (ls2[0] + ls2[1]) + (ls2[2] + ls2[3]);
        float mse = t / (float)TOT_ELEMS;
        float pck = t2 / (float)NKP;
        out[0] = mse + pck; // MSE_WEIGHT = SOFT_PCK_WEIGHT = 1.0
        out[1] = mse;
        out[2] = pck;
    }
}

extern "C" void kernel_launch(void* const* d_in, const int* in_sizes, int n_in,
                              void* d_out, int out_size, void* d_ws, size_t ws_size,
                              hipStream_t stream) {
    const float* pred = (const float*)d_in[0]; // (B,N,H,W)
    const float* gt   = (const float*)d_in[1]; // (B,N,H,W)
    const float* kp   = (const float*)d_in[2]; // (B,N,2)
    float* out = (float*)d_out;
    float2* partial = (float2*)d_ws;           // BLOCKS float2s = 16 KB

    combined_loss_partial<<<BLOCKS, THREADS, 0, stream>>>(
        (const float4*)pred, (const float4*)gt, pred, kp, partial);

    combined_loss_final<<<1, THREADS, 0, stream>>>(partial, out);
}

// Round 4
// 180.805 us; speedup vs baseline: 1.0799x; 1.0799x over previous
//
#include <hip/hip_runtime.h>

// Problem constants (from reference): B,N,H,W = 64,21,128,128
#define BB 64
#define NN 21
#define HH 128
#define WW 128
static constexpr long long TOT_ELEMS = (long long)BB * NN * HH * WW; // 22,020,096
static constexpr int NV4 = (int)(TOT_ELEMS / 4);                     // 5,505,024 float4s
static constexpr int NKP = BB * NN;                                  // 1344 keypoints

static constexpr int BLOCKS  = 2048; // 8 blocks/CU x 256 CUs
static constexpr int THREADS = 256;

// Native clang vector type: __builtin_nontemporal_load requires a pointer to
// scalar/vector-of-scalar, not HIP's float4 struct.
typedef float vfloat4 __attribute__((ext_vector_type(4)));

// Non-temporal float4 load: emits global_load_dwordx4 ... nt (no cache alloc).
// The pred/gt streams are read-once; NT avoids evicting the harness-restore's
// dirty lines (seen as 66 MB of WRITE_SIZE on a 16 KB-output kernel in R2).
__device__ __forceinline__ vfloat4 nt_load4(const vfloat4* p) {
    return __builtin_nontemporal_load(p);
}

// Kernel 1: grid-stride float4 MSE accumulation, 4-way unrolled.
// First NKP global threads also do the keypoint gather for soft-PCK.
// Each block writes its partial sums to its own ws slot (no init required).
__global__ __launch_bounds__(THREADS) void combined_loss_partial(
    const vfloat4* __restrict__ pred4,
    const vfloat4* __restrict__ gt4,
    const float*   __restrict__ pred,  // scalar view for the gather
    const float*   __restrict__ kp,    // (B,N,2) -> [x, y]
    float2* __restrict__ partial)      // partial[b] = {sum sq diff, sum (1-v)^2}
{
    const int tid    = blockIdx.x * blockDim.x + threadIdx.x;
    const int stride = gridDim.x * blockDim.x;

    float s0 = 0.0f, s1 = 0.0f, s2a = 0.0f, s3 = 0.0f;
    int i = tid;
    for (; i + 3 * stride < NV4; i += 4 * stride) {
        vfloat4 p0 = nt_load4(pred4 + i);
        vfloat4 p1 = nt_load4(pred4 + i + stride);
        vfloat4 p2 = nt_load4(pred4 + i + 2 * stride);
        vfloat4 p3 = nt_load4(pred4 + i + 3 * stride);
        vfloat4 g0 = nt_load4(gt4 + i);
        vfloat4 g1 = nt_load4(gt4 + i + stride);
        vfloat4 g2 = nt_load4(gt4 + i + 2 * stride);
        vfloat4 g3 = nt_load4(gt4 + i + 3 * stride);
        float d;
        d = p0.x - g0.x; s0 += d * d;  d = p0.y - g0.y; s0 += d * d;
        d = p0.z - g0.z; s0 += d * d;  d = p0.w - g0.w; s0 += d * d;
        d = p1.x - g1.x; s1 += d * d;  d = p1.y - g1.y; s1 += d * d;
        d = p1.z - g1.z; s1 += d * d;  d = p1.w - g1.w; s1 += d * d;
        d = p2.x - g2.x; s2a += d * d; d = p2.y - g2.y; s2a += d * d;
        d = p2.z - g2.z; s2a += d * d; d = p2.w - g2.w; s2a += d * d;
        d = p3.x - g3.x; s3 += d * d;  d = p3.y - g3.y; s3 += d * d;
        d = p3.z - g3.z; s3 += d * d;  d = p3.w - g3.w; s3 += d * d;
    }
    for (; i < NV4; i += stride) {
        vfloat4 p = nt_load4(pred4 + i);
        vfloat4 g = nt_load4(gt4 + i);
        float d;
        d = p.x - g.x; s0 += d * d;  d = p.y - g.y; s0 += d * d;
        d = p.z - g.z; s0 += d * d;  d = p.w - g.w; s0 += d * d;
    }
    float s = (s0 + s1) + (s2a + s3);

    // Soft-PCK gather: tid == b*N + n, heatmap base offset = tid*H*W.
    float s2 = 0.0f;
    if (tid < NKP) {
        float px = kp[2 * tid + 0];
        float py = kp[2 * tid + 1];
        // jnp.clip(v, 0, dim-1).astype(int32): clamp then truncate toward zero
        int xi = (int)fminf(fmaxf(px, 0.0f), (float)(WW - 1));
        int yi = (int)fminf(fmaxf(py, 0.0f), (float)(HH - 1));
        float v = pred[(long long)tid * HH * WW + (long long)yi * WW + xi];
        float dd = 1.0f - v;
        s2 = dd * dd;
    }

    // Wave-64 reduce
    #pragma unroll
    for (int off = 32; off > 0; off >>= 1) {
        s  += __shfl_down(s,  off, 64);
        s2 += __shfl_down(s2, off, 64);
    }

    __shared__ float ls[4], ls2[4]; // 256 threads / 64 = 4 waves
    const int lane = threadIdx.x & 63;
    const int wid  = threadIdx.x >> 6;
    if (lane == 0) { ls[wid] = s; ls2[wid] = s2; }
    __syncthreads();
    if (threadIdx.x == 0) {
        float t  = (ls[0] + ls[1]) + (ls[2] + ls[3]);
        float t2 = (ls2[0] + ls2[1]) + (ls2[2] + ls2[3]);
        partial[blockIdx.x] = make_float2(t, t2);
    }
}

// Kernel 2: one block reduces the per-block partials and writes out.
__global__ __launch_bounds__(THREADS) void combined_loss_final(
    const float2* __restrict__ partial,
    float* __restrict__ out)
{
    float s = 0.0f, s2 = 0.0f;
    for (int i = threadIdx.x; i < BLOCKS; i += THREADS) {
        float2 p = partial[i];
        s += p.x; s2 += p.y;
    }
    #pragma unroll
    for (int off = 32; off > 0; off >>= 1) {
        s  += __shfl_down(s,  off, 64);
        s2 += __shfl_down(s2, off, 64);
    }
    __shared__ float ls[4], ls2[4];
    const int lane = threadIdx.x & 63;
    const int wid  = threadIdx.x >> 6;
    if (lane == 0) { ls[wid] = s; ls2[wid] = s2; }
    __syncthreads();
    if (threadIdx.x == 0) {
        float t  = (ls[0] + ls[1]) + (ls[2] + ls[3]);
        float t2 = (ls2[0] + ls2[1]) + (ls2[2] + ls2[3]);
        float mse = t / (float)TOT_ELEMS;
        float pck = t2 / (float)NKP;
        out[0] = mse + pck; // MSE_WEIGHT = SOFT_PCK_WEIGHT = 1.0
        out[1] = mse;
        out[2] = pck;
    }
}

extern "C" void kernel_launch(void* const* d_in, const int* in_sizes, int n_in,
                              void* d_out, int out_size, void* d_ws, size_t ws_size,
                              hipStream_t stream) {
    const float* pred = (const float*)d_in[0]; // (B,N,H,W)
    const float* gt   = (const float*)d_in[1]; // (B,N,H,W)
    const float* kp   = (const float*)d_in[2]; // (B,N,2)
    float* out = (float*)d_out;
    float2* partial = (float2*)d_ws;           // BLOCKS float2s = 16 KB

    combined_loss_partial<<<BLOCKS, THREADS, 0, stream>>>(
        (const vfloat4*)pred, (const vfloat4*)gt, pred, kp, partial);

    combined_loss_final<<<1, THREADS, 0, stream>>>(partial, out);
}

// Round 5
// 175.348 us; speedup vs baseline: 1.1135x; 1.0311x over previous
//
#include <hip/hip_runtime.h>

// Problem constants (from reference): B,N,H,W = 64,21,128,128
#define BB 64
#define NN 21
#define HH 128
#define WW 128
static constexpr long long TOT_ELEMS = (long long)BB * NN * HH * WW; // 22,020,096
static constexpr int NV4 = (int)(TOT_ELEMS / 4);                     // 5,505,024 float4s
static constexpr int NKP = BB * NN;                                  // 1344 keypoints

// 5,505,024 float4 = 5376 windows of 1024 float4 (16 KB).
// 1792 blocks x 3 windows x 1024 == NV4 exactly -> no tail code.
static constexpr int THREADS = 256;
static constexpr int BLOCKS  = 1792;              // 7 blocks/CU x 256 CUs
static constexpr int WPB     = 3;                 // windows per block
static_assert((long long)BLOCKS * WPB * 1024 == NV4, "exact tiling");

// Native clang vector type: __builtin_nontemporal_load requires a pointer to
// scalar/vector-of-scalar, not HIP's float4 struct.
typedef float vfloat4 __attribute__((ext_vector_type(4)));

// Non-temporal load (global_load_dwordx4 ... nt): no cache allocation.
// Critical here: the harness re-poisons a 336 MB d_ws before every timed
// launch, leaving L3 full of dirty poison lines. Cached reads would allocate
// -> evict poison -> writeback storm (R2: 66 MB WRITE_SIZE, 2.3 TB/s). NT
// reads leave L3 alone (R4: kernel 67 -> <52 us).
__device__ __forceinline__ vfloat4 nt_load4(const vfloat4* p) {
    return __builtin_nontemporal_load(p);
}

// Kernel 1: block-contiguous MSE accumulation. Each block reads 3 contiguous
// 16 KB windows per stream; a wave's 8 in-flight loads are 4 KB apart (DRAM
// page-friendly), vs 8 MB apart in the R4 grid-stride version.
// First NKP global threads also do the keypoint gather for soft-PCK.
__global__ __launch_bounds__(THREADS) void combined_loss_partial(
    const vfloat4* __restrict__ pred4,
    const vfloat4* __restrict__ gt4,
    const float*   __restrict__ pred,  // scalar view for the gather
    const float*   __restrict__ kp,    // (B,N,2) -> [x, y]
    float2* __restrict__ partial)      // partial[b] = {sum sq diff, sum (1-v)^2}
{
    const int t    = threadIdx.x;
    const int base = blockIdx.x * (WPB * 1024) + t;

    float s0 = 0.0f, s1 = 0.0f, s2acc = 0.0f, s3 = 0.0f;
    #pragma unroll
    for (int k = 0; k < WPB; ++k) {
        const int idx = base + k * 1024;
        vfloat4 p0 = nt_load4(pred4 + idx);
        vfloat4 p1 = nt_load4(pred4 + idx + 256);
        vfloat4 p2 = nt_load4(pred4 + idx + 512);
        vfloat4 p3 = nt_load4(pred4 + idx + 768);
        vfloat4 g0 = nt_load4(gt4 + idx);
        vfloat4 g1 = nt_load4(gt4 + idx + 256);
        vfloat4 g2 = nt_load4(gt4 + idx + 512);
        vfloat4 g3 = nt_load4(gt4 + idx + 768);
        float d;
        d = p0.x - g0.x; s0 += d * d;    d = p0.y - g0.y; s0 += d * d;
        d = p0.z - g0.z; s0 += d * d;    d = p0.w - g0.w; s0 += d * d;
        d = p1.x - g1.x; s1 += d * d;    d = p1.y - g1.y; s1 += d * d;
        d = p1.z - g1.z; s1 += d * d;    d = p1.w - g1.w; s1 += d * d;
        d = p2.x - g2.x; s2acc += d * d; d = p2.y - g2.y; s2acc += d * d;
        d = p2.z - g2.z; s2acc += d * d; d = p2.w - g2.w; s2acc += d * d;
        d = p3.x - g3.x; s3 += d * d;    d = p3.y - g3.y; s3 += d * d;
        d = p3.z - g3.z; s3 += d * d;    d = p3.w - g3.w; s3 += d * d;
    }
    float s = (s0 + s1) + (s2acc + s3);

    // Soft-PCK gather: gid == b*N + n, heatmap base offset = gid*H*W.
    const int gid = blockIdx.x * THREADS + t;
    float s2 = 0.0f;
    if (gid < NKP) {
        float px = kp[2 * gid + 0];
        float py = kp[2 * gid + 1];
        // jnp.clip(v, 0, dim-1).astype(int32): clamp then truncate toward zero
        int xi = (int)fminf(fmaxf(px, 0.0f), (float)(WW - 1));
        int yi = (int)fminf(fmaxf(py, 0.0f), (float)(HH - 1));
        float v = pred[(long long)gid * HH * WW + (long long)yi * WW + xi];
        float dd = 1.0f - v;
        s2 = dd * dd;
    }

    // Wave-64 reduce
    #pragma unroll
    for (int off = 32; off > 0; off >>= 1) {
        s  += __shfl_down(s,  off, 64);
        s2 += __shfl_down(s2, off, 64);
    }

    __shared__ float ls[4], ls2[4]; // 256 threads / 64 = 4 waves
    const int lane = t & 63;
    const int wid  = t >> 6;
    if (lane == 0) { ls[wid] = s; ls2[wid] = s2; }
    __syncthreads();
    if (t == 0) {
        float tt  = (ls[0] + ls[1]) + (ls[2] + ls[3]);
        float tt2 = (ls2[0] + ls2[1]) + (ls2[2] + ls2[3]);
        partial[blockIdx.x] = make_float2(tt, tt2);
    }
}

// Kernel 2: one block reduces the per-block partials and writes out.
__global__ __launch_bounds__(THREADS) void combined_loss_final(
    const float2* __restrict__ partial,
    float* __restrict__ out)
{
    float s = 0.0f, s2 = 0.0f;
    for (int i = threadIdx.x; i < BLOCKS; i += THREADS) {
        float2 p = partial[i];
        s += p.x; s2 += p.y;
    }
    #pragma unroll
    for (int off = 32; off > 0; off >>= 1) {
        s  += __shfl_down(s,  off, 64);
        s2 += __shfl_down(s2, off, 64);
    }
    __shared__ float ls[4], ls2[4];
    const int lane = threadIdx.x & 63;
    const int wid  = threadIdx.x >> 6;
    if (lane == 0) { ls[wid] = s; ls2[wid] = s2; }
    __syncthreads();
    if (threadIdx.x == 0) {
        float t  = (ls[0] + ls[1]) + (ls[2] + ls[3]);
        float t2 = (ls2[0] + ls2[1]) + (ls2[2] + ls2[3]);
        float mse = t / (float)TOT_ELEMS;
        float pck = t2 / (float)NKP;
        out[0] = mse + pck; // MSE_WEIGHT = SOFT_PCK_WEIGHT = 1.0
        out[1] = mse;
        out[2] = pck;
    }
}

extern "C" void kernel_launch(void* const* d_in, const int* in_sizes, int n_in,
                              void* d_out, int out_size, void* d_ws, size_t ws_size,
                              hipStream_t stream) {
    const float* pred = (const float*)d_in[0]; // (B,N,H,W)
    const float* gt   = (const float*)d_in[1]; // (B,N,H,W)
    const float* kp   = (const float*)d_in[2]; // (B,N,2)
    float* out = (float*)d_out;
    float2* partial = (float2*)d_ws;           // BLOCKS float2s = 14 KB

    combined_loss_partial<<<BLOCKS, THREADS, 0, stream>>>(
        (const vfloat4*)pred, (const vfloat4*)gt, pred, kp, partial);

    combined_loss_final<<<1, THREADS, 0, stream>>>(partial, out);
}